// Round 4
// baseline (3824.944 us; speedup 1.0000x reference)
//
#include <hip/hip_runtime.h>

#define THREADS 256
#define TOK 16
#define XS 260   // 256 dims + 4 pad
#define DELTA 2e-3f

// Output section bases (element offsets into flat d_out), reference return order:
// quantized (8,4096,1024) | indices (8,4096,4) | quant (8,4096,4,256) |
// avg_code_probs (8,4096,1024) | x (8,4096,1024)
#define OFF_IDX 33554432ull
#define OFF_Q2  33685504ull
#define OFF_AVG 67239936ull
#define OFF_X   100794368ull

// Candidate replica of the reference's fp32 accumulation order:
// BLAS/XLA:CPU sgemm micro-kernel per-element order = single forward FMA
// chain over d ascending (one k-block since K=256; product not separately
// rounded, one accumulator register).
__device__ __forceinline__ float ref_dot256(const float* __restrict__ xr,
                                            const float* __restrict__ cr) {
  float acc = 0.f;
#pragma unroll
  for (int d = 0; d < 256; ++d)
    acc = __fmaf_rn(xr[d], cr[d], acc);
  return acc;
}

__global__ __launch_bounds__(THREADS)
void ahq_fused(const float* __restrict__ x,
               const float* __restrict__ cb,
               const float* __restrict__ temp,
               float* __restrict__ out) {
  __shared__ float xs[TOK * XS];
  __shared__ float red_m[4][8];
  __shared__ float red_sum[4][8];
  __shared__ int   clist[TOK][16];
  __shared__ int   ccnt[TOK];
  __shared__ int   idx_all[TOK][4];

  const int t    = threadIdx.x;
  const int tg   = t >> 7;      // token group: tokens tg*8 .. tg*8+7
  const int c    = t & 127;     // code lane: codes c + 128*j
  const int wave = t >> 6;
  const int lane = t & 63;
  const int bs0  = blockIdx.x * TOK;

  const float tau = fmaxf(temp[0], 0.04f);
  const float invtau = 1.0f / tau;

  float* out_q   = out;
  float* out_idx = out + OFF_IDX;
  float* out_q2  = out + OFF_Q2;
  float* out_avg = out + OFF_AVG;
  float* out_x   = out + OFF_X;

  float avg[8][8];
#pragma unroll
  for (int i = 0; i < 8; ++i)
#pragma unroll
    for (int j = 0; j < 8; ++j) avg[i][j] = 0.f;

  for (int l = 0; l < 4; ++l) {
    if (t < TOK) ccnt[t] = 0;
    // ---- stage this layer's X slab (16 tokens x 256 dims) + x passthrough ----
    {
      const float4* xg = (const float4*)x;
      float4* xo = (float4*)out_x;
#pragma unroll
      for (int it = 0; it < 4; ++it) {
        int f = t + THREADS * it;        // 0..1023 float4s of [16][64]
        int row = f >> 6, col4 = f & 63;
        size_t g = (size_t)(bs0 + row) * 256 + (size_t)l * 64 + col4;
        float4 v = xg[g];
        float* dst = &xs[row * XS + col4 * 4];
        dst[0] = v.x; dst[1] = v.y; dst[2] = v.z; dst[3] = v.w;
        xo[g] = v;                        // x passthrough, coalesced
      }
    }
    __syncthreads();   // S1

    // ---- GEMM: sim[i][j] = dot(x[m_i, l*256:+256], cb[l, c+128j, :]) ----
    float sim[8][8];
#pragma unroll
    for (int i = 0; i < 8; ++i)
#pragma unroll
      for (int j = 0; j < 8; ++j) sim[i][j] = 0.f;

    const float* cbase = cb + ((size_t)l << 18) + (size_t)c * 256;
    for (int d = 0; d < 256; d += 4) {
      float4 cv[8];
#pragma unroll
      for (int j = 0; j < 8; ++j)
        cv[j] = *(const float4*)(cbase + ((size_t)j << 15) + d);
#pragma unroll
      for (int i = 0; i < 8; ++i) {
        float4 xv = *(const float4*)(&xs[(tg * 8 + i) * XS + d]); // wave-uniform broadcast
#pragma unroll
        for (int j = 0; j < 8; ++j)
          sim[i][j] += xv.x * cv[j].x + xv.y * cv[j].y + xv.z * cv[j].z + xv.w * cv[j].w;
      }
    }

    // ---- per-token max (value only) ----
    float M[8];
#pragma unroll
    for (int i = 0; i < 8; ++i) {
      float m = sim[i][0];
#pragma unroll
      for (int j = 1; j < 8; ++j) m = fmaxf(m, sim[i][j]);
      M[i] = m;
    }
#pragma unroll
    for (int off = 32; off > 0; off >>= 1)
#pragma unroll
      for (int i = 0; i < 8; ++i) M[i] = fmaxf(M[i], __shfl_xor(M[i], off, 64));
    if (lane == 0)
#pragma unroll
      for (int i = 0; i < 8; ++i) red_m[wave][i] = M[i];
    __syncthreads();   // S2
#pragma unroll
    for (int i = 0; i < 8; ++i)
      M[i] = fmaxf(red_m[tg * 2][i], red_m[tg * 2 + 1][i]);

    // ---- push delta-window candidates (before sim is overwritten by exp) ----
#pragma unroll
    for (int i = 0; i < 8; ++i) {
      int m = tg * 8 + i;
      float thr = M[i] - DELTA;
#pragma unroll
      for (int j = 0; j < 8; ++j) {
        if (sim[i][j] >= thr) {
          int pos = atomicAdd(&ccnt[m], 1);
          if (pos < 16) clist[m][pos] = c + (j << 7);
        }
      }
    }

    // ---- exp + row sum (softmax(sim/tau) via exp((s-M)*invtau)) ----
    float S[8];
#pragma unroll
    for (int i = 0; i < 8; ++i) {
      float s = 0.f;
#pragma unroll
      for (int j = 0; j < 8; ++j) {
        float e = __expf((sim[i][j] - M[i]) * invtau);
        sim[i][j] = e; s += e;
      }
      S[i] = s;
    }
#pragma unroll
    for (int off = 32; off > 0; off >>= 1)
#pragma unroll
      for (int i = 0; i < 8; ++i) S[i] += __shfl_xor(S[i], off, 64);
    if (lane == 0)
#pragma unroll
      for (int i = 0; i < 8; ++i) red_sum[wave][i] = S[i];
    __syncthreads();   // S3

    // ---- avg_code_probs accumulation ----
#pragma unroll
    for (int i = 0; i < 8; ++i) {
      float Z = red_sum[tg * 2][i] + red_sum[tg * 2 + 1][i];
      float invZ = 1.0f / Z;
#pragma unroll
      for (int j = 0; j < 8; ++j) avg[i][j] += sim[i][j] * invZ;
    }

    // ---- argmax decision: sole candidate, or ref-order fp32 recompute ----
    if ((t & 15) == 0) {
      int m = t >> 4;
      int cnt = ccnt[m]; if (cnt > 16) cnt = 16;
      int fin;
      if (cnt == 1) {
        fin = clist[m][0];
      } else {
        float best = -3.4e38f; int bi = 0x7fffffff;
        for (int q = 0; q < cnt; ++q) {
          int ci = clist[m][q];
          float s = ref_dot256(&xs[m * XS], cb + ((size_t)l << 18) + (size_t)ci * 256);
          if (s > best || (s == best && ci < bi)) { best = s; bi = ci; }
        }
        fin = bi;
      }
      out_idx[(size_t)(bs0 + m) * 4 + l] = (float)fin;
      idx_all[m][l] = fin;
    }
    __syncthreads();   // S4: protect xs restage, red_*/ccnt reuse, idx_all
  }

  // ---- avg_code_probs: lanes consecutive in k -> coalesced scalar stores ----
#pragma unroll
  for (int i = 0; i < 8; ++i) {
    size_t rb = (size_t)(bs0 + tg * 8 + i) * 1024 + c;
#pragma unroll
    for (int j = 0; j < 8; ++j)
      out_avg[rb + (j << 7)] = avg[i][j] * 0.25f;
  }

  // ---- hard_q gather -> quantized AND quant (identical flat content) ----
  {
    const float4* cb4 = (const float4*)cb;
    float4* o0 = (float4*)out_q;
    float4* o2 = (float4*)out_q2;
#pragma unroll
    for (int it = 0; it < 16; ++it) {
      int f = t + THREADS * it;          // 0..4095 float4s of [16][256]
      int row = f >> 8, col4 = f & 255;
      int ll = col4 >> 6, d4 = col4 & 63;
      int idx = idx_all[row][ll];
      float4 v = cb4[(((size_t)ll * 1024 + idx) << 6) + d4];
      size_t o = (size_t)(bs0 + row) * 256 + col4;
      o0[o] = v;
      o2[o] = v;
    }
  }
}

extern "C" void kernel_launch(void* const* d_in, const int* in_sizes, int n_in,
                              void* d_out, int out_size, void* d_ws, size_t ws_size,
                              hipStream_t stream) {
  const float* x    = (const float*)d_in[0];
  const float* cb   = (const float*)d_in[1];
  const float* temp = (const float*)d_in[2];
  float* out = (float*)d_out;
  dim3 grid(32768 / TOK);   // B*S / tokens-per-block
  hipLaunchKernelGGL(ahq_fused, grid, dim3(THREADS), 0, stream, x, cb, temp, out);
}